// Round 4
// baseline (231.504 us; speedup 1.0000x reference)
//
#include <hip/hip_runtime.h>
#include <math.h>

// Problem constants (from reference)
#define B_ 4096
#define T_ 1024
#define I_ 6
#define H_ 2
#define L_ 5
#define G_ 8            // 4*H packed gates, PyTorch order: rows 0-1=i, 2-3=f, 4-5=g, 6-7=o
#define S_ (T_ + L_ - 1) // 1028 pipelined steps

// Only batch element B-1 affects the output (softmax(seq[-1,-1])); LSTM is
// batch-independent -> process exactly one sequence.
//
// Serial phase: lane = 2*l + j (layer l, hidden unit j). Cross-lane via DPP:
//   hin0 = row_shr:2(h)      (prev layer, own unit)
//   hin1 = row_shr:2(hoth)   (prev layer, other unit)  -- parallel, no dpp chain
//   hoth = quad_perm-swap(h) (own layer, other unit)
// All weights/biases/pre0 pre-scaled by -log2e (i,f,o) or -2log2e (g) so
// every activation is exp2 -> add -> rcp with no multiply. Cell state is
// kept PRE-SCALED: cs = -2log2e * c, so tanh(c) = 2*rcp(1+exp2(cs)) - 1
// and cs = fv*cs_prev + m with m = -2log2e*iv*gv built off the f critical
// path. h = ov*tanh(c) = fma(2*ov, rh, -ov) with 2*ov off-path.
// Critical cycle: 4 fma accum -> exp2 -> add -> rcp -> fma(cs) -> exp2 ->
// add -> rcp -> fma(h) = 12 dependent VALU levels per step.

#define K1 1.4426950408889634f   /* log2(e)   */
#define K2 2.8853900817779268f   /* 2*log2(e) */

template <int CTRL>
__device__ __forceinline__ float dppf(float v) {
    int i = __float_as_int(v);
    int r = __builtin_amdgcn_update_dpp(i, i, CTRL, 0xF, 0xF, false);
    return __int_as_float(r);
}
#define DPP_SHR2 0x112   /* row_shr:2            */
#define DPP_SWAP 0xB1    /* quad_perm [1,0,3,2]  */

__global__ __launch_bounds__(256) void lstm_kernel(
    const float* __restrict__ x,
    const float* __restrict__ Wih0,
    const float* __restrict__ Wih,
    const float* __restrict__ Whh,
    const float* __restrict__ bih,
    const float* __restrict__ bhh,
    float* __restrict__ out)
{
    // pre0[t*8 + {i,f,g,o} ordered as j*4+q]: pre-scaled layer-0 preactivation.
    // 8 pad t-slots of zeros so distance-8 prefetch never reads garbage.
    __shared__ float pre0[(T_ + 8) * G_];
    // Per-serial-lane (2..9) bias block: 4 identical float4 copies at 32B
    // spacing (ds offsets 0/32/64/96), block stride 36 floats to spread banks.
    __shared__ float zrep[8 * 36 + 12];

    const int tid = threadIdx.x;
    const float* xrow = x + (size_t)(B_ - 1) * T_ * I_;   // x[B-1, :, :]
    const float sc[4] = { -K1, -K1, -K2, -K1 };           // i, f, g, o row scales

    // ---- parallel phase: pre-scaled layer-0 input projections for all t
    float w0s[G_][I_];
    float b0s[G_];
    #pragma unroll
    for (int j = 0; j < 2; ++j)
        #pragma unroll
        for (int q = 0; q < 4; ++q) {
            const int m = j * 4 + q, row = 2 * q + j;
            const float s = sc[q];
            b0s[m] = s * (bih[row] + bhh[row]);
            #pragma unroll
            for (int k = 0; k < I_; ++k) w0s[m][k] = s * Wih0[row * I_ + k];
        }
    for (int t = tid; t < T_; t += 256) {
        float xv[I_];
        #pragma unroll
        for (int k = 0; k < I_; ++k) xv[k] = xrow[t * I_ + k];
        #pragma unroll
        for (int m = 0; m < G_; ++m) {
            float acc = b0s[m];
            #pragma unroll
            for (int k = 0; k < I_; ++k) acc = fmaf(xv[k], w0s[m][k], acc);
            pre0[t * G_ + m] = acc;
        }
    }
    if (tid < 64) pre0[T_ * G_ + tid] = 0.f;   // zero pad slots
    if (tid < 128) {
        // zrep for serial lane zl+2: layer l=(zl+2)>>1, unit j=(zl+2)&1
        const int zl = tid >> 4, k = (tid >> 2) & 3, q = tid & 3;
        const int l = (zl + 2) >> 1, j = (zl + 2) & 1, row = 2 * q + j;
        zrep[zl * 36 + k * 8 + q] = sc[q] * (bih[l * G_ + row] + bhh[l * G_ + row]);
    }
    __syncthreads();
    if (tid >= 64) return;   // serial phase: one wave

    // ---- per-lane constants (pre-scaled weights)
    const int lane = tid;
    const int lraw = lane >> 1;
    const int l = (lraw < L_) ? lraw : (L_ - 1);   // clamp for lanes >= 10
    const int j = lane & 1;

    float wOwn[4], wOth[4], wiOwn[4], wiOth[4];
    #pragma unroll
    for (int q = 0; q < 4; ++q) {
        const int row = 2 * q + j;
        const float s = sc[q];
        wOwn[q] = s * Whh[l * (G_ * H_) + row * H_ + j];
        wOth[q] = s * Whh[l * (G_ * H_) + row * H_ + (1 - j)];
        if (l > 0) {
            wiOwn[q] = s * Wih[(l - 1) * (G_ * H_) + row * H_ + j];
            wiOth[q] = s * Wih[(l - 1) * (G_ * H_) + row * H_ + (1 - j)];
        } else {
            wiOwn[q] = 0.f; wiOth[q] = 0.f;   // layer 0: input term is in pre0
        }
    }

    // Per-lane LDS stream: lanes 0,1 walk pre0 (128B per 4-step block);
    // lanes 2-9 sit on their replicated bias block (stride 0).
    const char* pb;
    int stB;
    if (lane < 2) { pb = (const char*)&pre0[lane * 4]; stB = 128; }
    else {
        const int zl = (lane < 10 ? lane : 9) - 2;
        pb = (const char*)&zrep[zl * 36]; stB = 0;
    }

#define LOADBLK(A,B,C,D)                                                    \
    { A = *(const float4*)(pb);      B = *(const float4*)(pb + 32);         \
      C = *(const float4*)(pb + 64); D = *(const float4*)(pb + 96);         \
      pb += stB; }

    float h = 0.f, cs = 0.f;          // cs = -2log2e * c  (pre-scaled cell)
    float hoth = 0.f, hin0 = 0.f, hin1 = 0.f;

    // Accumulation order: i and g chains first (their results feed the
    // off-path m computation), then f (the true critical input to cs),
    // then o. Each accum is a 4-deep fma chain ordered by input
    // availability: h (ready first), hoth, hin0, hin1 (parallel dpps).
#define STEP_CORE(QX)                                                       \
        float ai = fmaf(wOwn[0], h, (QX).x);                                \
        float ag = fmaf(wOwn[2], h, (QX).z);                                \
        float af = fmaf(wOwn[1], h, (QX).y);                                \
        float ao = fmaf(wOwn[3], h, (QX).w);                                \
        ai = fmaf(wOth[0], hoth, ai);                                       \
        ag = fmaf(wOth[2], hoth, ag);                                       \
        af = fmaf(wOth[1], hoth, af);                                       \
        ao = fmaf(wOth[3], hoth, ao);                                       \
        ai = fmaf(wiOwn[0], hin0, ai);                                      \
        ag = fmaf(wiOwn[2], hin0, ag);                                      \
        af = fmaf(wiOwn[1], hin0, af);                                      \
        ao = fmaf(wiOwn[3], hin0, ao);                                      \
        ai = fmaf(wiOth[0], hin1, ai);                                      \
        ag = fmaf(wiOth[2], hin1, ag);                                      \
        af = fmaf(wiOth[1], hin1, af);                                      \
        ao = fmaf(wiOth[3], hin1, ao);                                      \
        const float ei = __builtin_amdgcn_exp2f(ai);                        \
        const float eg = __builtin_amdgcn_exp2f(ag);                        \
        const float ef = __builtin_amdgcn_exp2f(af);                        \
        const float eo = __builtin_amdgcn_exp2f(ao);                        \
        const float iv = __builtin_amdgcn_rcpf(1.0f + ei);                  \
        const float r2 = __builtin_amdgcn_rcpf(1.0f + eg);                  \
        const float fv = __builtin_amdgcn_rcpf(1.0f + ef);                  \
        const float ov = __builtin_amdgcn_rcpf(1.0f + eo);                  \
        const float p  = K2 * iv;            /* off f-path */               \
        const float pp = p + p;                                             \
        const float m  = fmaf(-pp, r2, p);   /* m = -K2*iv*(2*r2-1) */      \
        const float ovx2 = ov + ov;          /* off path */                 \
        const float csn = fmaf(fv, cs, m);                                  \
        const float eh = __builtin_amdgcn_exp2f(csn);                       \
        const float rh = __builtin_amdgcn_rcpf(1.0f + eh);                  \
        const float hn = fmaf(ovx2, rh, -ov);  /* ov*tanh(c) */

#define STEP(QX)                                                            \
    {                                                                       \
        STEP_CORE(QX)                                                       \
        cs = csn;                                                           \
        h  = hn;                                                            \
        hoth = dppf<DPP_SWAP>(h);                                           \
        hin0 = dppf<DPP_SHR2>(h);                                           \
        hin1 = dppf<DPP_SHR2>(hoth);                                        \
    }

#define STEP_M(QX, S)                                                       \
    {                                                                       \
        STEP_CORE(QX)                                                       \
        const bool valid = ((S) >= lraw);                                   \
        cs = valid ? csn : 0.0f;                                            \
        h  = valid ? hn  : 0.0f;                                            \
        hoth = dppf<DPP_SWAP>(h);                                           \
        hin0 = dppf<DPP_SHR2>(h);                                           \
        hin1 = dppf<DPP_SHR2>(hoth);                                        \
    }

    float4 qa0, qa1, qa2, qa3, qb0, qb1, qb2, qb3;
    LOADBLK(qa0, qa1, qa2, qa3)        // block 0: steps 0..3
    LOADBLK(qb0, qb1, qb2, qb3)        // block 1: steps 4..7

    // peeled masked warmup (t<0 only possible for s<4)
    STEP_M(qa0, 0) STEP_M(qa1, 1) STEP_M(qa2, 2) STEP_M(qa3, 3)

    // steady: steps 4..1027, 128 iterations x 8 steps, double-buffered.
    // Drain (t>=T) needs no mask: stale h only flows toward higher layers
    // at t>=T and never reaches the (layer 4, t=T-1) output; pre0 pad rows
    // are zero.
    for (int it = 0; it < 128; ++it) {
        LOADBLK(qa0, qa1, qa2, qa3)    // block 2+2it (steps +8)
        STEP(qb0) STEP(qb1) STEP(qb2) STEP(qb3)
        LOADBLK(qb0, qb1, qb2, qb3)    // block 3+2it
        STEP(qa0) STEP(qa1) STEP(qa2) STEP(qa3)
    }
#undef STEP
#undef STEP_M
#undef STEP_CORE
#undef LOADBLK

    // layer 4 = lanes 8 (unit 0) and 9 (unit 1)
    const float hf0 = __shfl(h, 8, 64);
    const float hf1 = __shfl(h, 9, 64);
    if (lane == 0) {
        const float mx = fmaxf(hf0, hf1);
        const float e0 = __builtin_amdgcn_exp2f(K1 * (hf0 - mx));
        const float e1 = __builtin_amdgcn_exp2f(K1 * (hf1 - mx));
        const float inv = 1.f / (e0 + e1);
        out[0] = e0 * inv;
        out[1] = e1 * inv;
    }
}

extern "C" void kernel_launch(void* const* d_in, const int* in_sizes, int n_in,
                              void* d_out, int out_size, void* d_ws, size_t ws_size,
                              hipStream_t stream) {
    const float* x    = (const float*)d_in[0];
    // d_in[1] = hidden (unused by the reference forward)
    const float* Wih0 = (const float*)d_in[2];
    const float* Wih  = (const float*)d_in[3];
    const float* Whh  = (const float*)d_in[4];
    const float* bih  = (const float*)d_in[5];
    const float* bhh  = (const float*)d_in[6];
    float* out = (float*)d_out;

    lstm_kernel<<<1, 256, 0, stream>>>(x, Wih0, Wih, Whh, bih, bhh, out);
}

// Round 5
// 217.717 us; speedup vs baseline: 1.0633x; 1.0633x over previous
//
#include <hip/hip_runtime.h>
#include <math.h>

// Problem constants (from reference)
#define B_ 4096
#define T_ 1024
#define I_ 6
#define H_ 2
#define L_ 5
#define G_ 8            // 4*H packed gates, PyTorch order: rows 0-1=i, 2-3=f, 4-5=g, 6-7=o

// Only batch element B-1 affects the output (softmax(seq[-1,-1])); LSTM is
// batch-independent -> process exactly one sequence.
//
// Serial phase: lane = 2*l + j (layer l, hidden unit j). Cross-lane via DPP
// computed at step end: hoth = swap(h), hin0 = shr2(h), hin1 = shr2(hoth).
// Accumulation enters h FIRST, then hoth, hin0, hin1 - the dpp'd inputs are
// ready 1-2 fma-levels after h, so dpp latency hides under the chain.
// All weights/biases/pre0 pre-scaled by -log2e (i,f,o) or -2log2e (g):
//   sigma(a) = rcp(1 + exp2(a'))
// Cell kept pre-scaled: cs = -2log2e*c, so tanh(c) = 2*rcp(1+exp2(cs))-1 and
// cs' = fv*cs + m, m = fma(-2K2*iv, r2, K2*iv)  (both muls parallel, off the
// f path), hn = fma(2ov, rh, -ov).
// Layer-0 preactivation stream: 4 register buffers x 4 steps (prefetch
// distance 12-16 steps, 16 ds_read_b128 outstanding) so lgkm waits never
// stall the head of the loop.

typedef float v2f __attribute__((ext_vector_type(2)));

#define K1 1.4426950408889634f   /* log2(e)   */
#define K2 2.8853900817779268f   /* 2*log2(e) */

template <int CTRL>
__device__ __forceinline__ float dppf(float v) {
    int i = __float_as_int(v);
    int r = __builtin_amdgcn_update_dpp(i, i, CTRL, 0xF, 0xF, false);
    return __int_as_float(r);
}
#define DPP_SHR2 0x112   /* row_shr:2            */
#define DPP_SWAP 0xB1    /* quad_perm [1,0,3,2]  */

__global__ __launch_bounds__(256) void lstm_kernel(
    const float* __restrict__ x,
    const float* __restrict__ Wih0,
    const float* __restrict__ Wih,
    const float* __restrict__ Whh,
    const float* __restrict__ bih,
    const float* __restrict__ bhh,
    float* __restrict__ out)
{
    // pre0[t*8 + j*4 + q], q in {i,f,g,o}: pre-scaled layer-0 preactivations.
    // 20 pad t-slots of zeros: the 4-buffer pipeline loads blocks 0..259,
    // i.e. t up to 1039 (+1 float4 for lane 1).
    __shared__ float pre0[(T_ + 20) * G_];
    // Per-serial-lane (2..9) bias block: 4 identical float4 copies at 32B
    // spacing (ds offsets 0/32/64/96), block stride 36 floats to spread banks.
    __shared__ float zrep[8 * 36 + 12];

    const int tid = threadIdx.x;
    const float* xrow = x + (size_t)(B_ - 1) * T_ * I_;   // x[B-1, :, :]
    const float sc[4] = { -K1, -K1, -K2, -K1 };           // i, f, g, o row scales

    // ---- parallel phase: pre-scaled layer-0 input projections for all t
    float w0s[G_][I_];
    float b0s[G_];
    #pragma unroll
    for (int j = 0; j < 2; ++j)
        #pragma unroll
        for (int q = 0; q < 4; ++q) {
            const int m = j * 4 + q, row = 2 * q + j;
            const float s = sc[q];
            b0s[m] = s * (bih[row] + bhh[row]);
            #pragma unroll
            for (int k = 0; k < I_; ++k) w0s[m][k] = s * Wih0[row * I_ + k];
        }
    for (int t = tid; t < T_; t += 256) {
        float xv[I_];
        #pragma unroll
        for (int k = 0; k < I_; ++k) xv[k] = xrow[t * I_ + k];
        #pragma unroll
        for (int m = 0; m < G_; ++m) {
            float acc = b0s[m];
            #pragma unroll
            for (int k = 0; k < I_; ++k) acc = fmaf(xv[k], w0s[m][k], acc);
            pre0[t * G_ + m] = acc;
        }
    }
    if (tid < 160) pre0[T_ * G_ + tid] = 0.f;   // zero all pad slots
    if (tid < 128) {
        // zrep for serial lane zl+2: layer l=(zl+2)>>1, unit j=(zl+2)&1
        const int zl = tid >> 4, k = (tid >> 2) & 3, q = tid & 3;
        const int l = (zl + 2) >> 1, j = (zl + 2) & 1, row = 2 * q + j;
        zrep[zl * 36 + k * 8 + q] = sc[q] * (bih[l * G_ + row] + bhh[l * G_ + row]);
    }
    __syncthreads();
    if (tid >= 64) return;   // serial phase: one wave

    // ---- per-lane constants (pre-scaled weights)
    const int lane = tid;
    const int lraw = lane >> 1;
    const int l = (lraw < L_) ? lraw : (L_ - 1);   // clamp for lanes >= 10
    const int j = lane & 1;

    float wOwn[4], wOth[4], wiOwn[4], wiOth[4];
    #pragma unroll
    for (int q = 0; q < 4; ++q) {
        const int row = 2 * q + j;
        const float s = sc[q];
        wOwn[q] = s * Whh[l * (G_ * H_) + row * H_ + j];
        wOth[q] = s * Whh[l * (G_ * H_) + row * H_ + (1 - j)];
        if (l > 0) {
            wiOwn[q] = s * Wih[(l - 1) * (G_ * H_) + row * H_ + j];
            wiOth[q] = s * Wih[(l - 1) * (G_ * H_) + row * H_ + (1 - j)];
        } else {
            wiOwn[q] = 0.f; wiOth[q] = 0.f;   // layer 0: input term is in pre0
        }
    }
    const v2f wOwn01  = { wOwn[0],  wOwn[1]  }, wOwn23  = { wOwn[2],  wOwn[3]  };
    const v2f wOth01  = { wOth[0],  wOth[1]  }, wOth23  = { wOth[2],  wOth[3]  };
    const v2f wiOwn01 = { wiOwn[0], wiOwn[1] }, wiOwn23 = { wiOwn[2], wiOwn[3] };
    const v2f wiOth01 = { wiOth[0], wiOth[1] }, wiOth23 = { wiOth[2], wiOth[3] };

    // Per-lane LDS stream: lanes 0,1 walk pre0 (128B per 4-step block);
    // lanes 2-9 sit on their replicated bias block (stride 0).
    const char* pb;
    int stB;
    if (lane < 2) { pb = (const char*)&pre0[lane * 4]; stB = 128; }
    else {
        const int zl = (lane < 10 ? lane : 9) - 2;
        pb = (const char*)&zrep[zl * 36]; stB = 0;
    }

#define LOADBLK(A,B,C,D)                                                    \
    { A = *(const float4*)(pb);      B = *(const float4*)(pb + 32);         \
      C = *(const float4*)(pb + 64); D = *(const float4*)(pb + 96);         \
      pb += stB; }

    float h = 0.f, cs = 0.f;          // cs = -2log2e * c  (pre-scaled cell)
    float hoth = 0.f, hin0 = 0.f, hin1 = 0.f;

#define STEP_CORE(QX)                                                       \
        v2f a01 = { (QX).x, (QX).y };   /* gates i, f */                    \
        v2f a23 = { (QX).z, (QX).w };   /* gates g, o */                    \
        const v2f hv = { h, h };                                            \
        a01 = __builtin_elementwise_fma(wOwn01, hv, a01);                   \
        a23 = __builtin_elementwise_fma(wOwn23, hv, a23);                   \
        const v2f hothv = { hoth, hoth };                                   \
        a01 = __builtin_elementwise_fma(wOth01, hothv, a01);                \
        a23 = __builtin_elementwise_fma(wOth23, hothv, a23);                \
        const v2f hin0v = { hin0, hin0 };                                   \
        a01 = __builtin_elementwise_fma(wiOwn01, hin0v, a01);               \
        a23 = __builtin_elementwise_fma(wiOwn23, hin0v, a23);               \
        const v2f hin1v = { hin1, hin1 };                                   \
        a01 = __builtin_elementwise_fma(wiOth01, hin1v, a01);               \
        a23 = __builtin_elementwise_fma(wiOth23, hin1v, a23);               \
        const float ei = __builtin_amdgcn_exp2f(a01.x);                     \
        const float ef = __builtin_amdgcn_exp2f(a01.y);                     \
        const float eg = __builtin_amdgcn_exp2f(a23.x);                     \
        const float eo = __builtin_amdgcn_exp2f(a23.y);                     \
        const float iv = __builtin_amdgcn_rcpf(1.0f + ei);                  \
        const float fv = __builtin_amdgcn_rcpf(1.0f + ef);                  \
        const float r2 = __builtin_amdgcn_rcpf(1.0f + eg);                  \
        const float ov = __builtin_amdgcn_rcpf(1.0f + eo);                  \
        const float p  = K2 * iv;              /* parallel muls, off path */\
        const float pp = (-2.0f * K2) * iv;                                 \
        const float m  = fmaf(pp, r2, p);      /* -K2*iv*(2*r2-1) */        \
        const float ovx2 = ov + ov;            /* off path */               \
        const float csn = fmaf(fv, cs, m);                                  \
        const float eh = __builtin_amdgcn_exp2f(csn);                       \
        const float rh = __builtin_amdgcn_rcpf(1.0f + eh);                  \
        const float hn = fmaf(ovx2, rh, -ov);  /* ov*tanh(c) */

#define STEP(QX)                                                            \
    {                                                                       \
        STEP_CORE(QX)                                                       \
        cs = csn;                                                           \
        h  = hn;                                                            \
        hoth = dppf<DPP_SWAP>(h);                                           \
        hin0 = dppf<DPP_SHR2>(h);                                           \
        hin1 = dppf<DPP_SHR2>(hoth);                                        \
    }

#define STEP_M(QX, S)                                                       \
    {                                                                       \
        STEP_CORE(QX)                                                       \
        const bool valid = ((S) >= lraw);                                   \
        cs = valid ? csn : 0.0f;                                            \
        h  = valid ? hn  : 0.0f;                                            \
        hoth = dppf<DPP_SWAP>(h);                                           \
        hin0 = dppf<DPP_SHR2>(h);                                           \
        hin1 = dppf<DPP_SHR2>(hoth);                                        \
    }

    // 4 register buffers x 4 steps: prefetch distance 12-16 steps.
    float4 A0,A1,A2,A3, B0,B1,B2,B3, C0,C1,C2,C3, D0,D1,D2,D3;
    LOADBLK(A0,A1,A2,A3)   // block 0 (steps 0-3)
    LOADBLK(B0,B1,B2,B3)   // block 1
    LOADBLK(C0,C1,C2,C3)   // block 2
    LOADBLK(D0,D1,D2,D3)   // block 3

    // peeled masked warmup (t<0 only possible for s<4)
    STEP_M(A0, 0) STEP_M(A1, 1) STEP_M(A2, 2) STEP_M(A3, 3)

    // steady: steps 4..1027 = 64 iterations x 16 steps.
    // Drain (t>=T) needs no mask: stale h only flows toward higher layers at
    // t>=T and never reaches the (layer 4, t=T-1) output; pre0 pads are zero.
    for (int it = 0; it < 64; ++it) {
        LOADBLK(A0,A1,A2,A3)           // block 4+4it
        STEP(B0) STEP(B1) STEP(B2) STEP(B3)
        LOADBLK(B0,B1,B2,B3)           // block 5+4it
        STEP(C0) STEP(C1) STEP(C2) STEP(C3)
        LOADBLK(C0,C1,C2,C3)           // block 6+4it
        STEP(D0) STEP(D1) STEP(D2) STEP(D3)
        LOADBLK(D0,D1,D2,D3)           // block 7+4it
        STEP(A0) STEP(A1) STEP(A2) STEP(A3)
    }
#undef STEP
#undef STEP_M
#undef STEP_CORE
#undef LOADBLK

    // layer 4 = lanes 8 (unit 0) and 9 (unit 1)
    const float hf0 = __shfl(h, 8, 64);
    const float hf1 = __shfl(h, 9, 64);
    if (lane == 0) {
        const float mx = fmaxf(hf0, hf1);
        const float e0 = __builtin_amdgcn_exp2f(K1 * (hf0 - mx));
        const float e1 = __builtin_amdgcn_exp2f(K1 * (hf1 - mx));
        const float inv = 1.f / (e0 + e1);
        out[0] = e0 * inv;
        out[1] = e1 * inv;
    }
}

extern "C" void kernel_launch(void* const* d_in, const int* in_sizes, int n_in,
                              void* d_out, int out_size, void* d_ws, size_t ws_size,
                              hipStream_t stream) {
    const float* x    = (const float*)d_in[0];
    // d_in[1] = hidden (unused by the reference forward)
    const float* Wih0 = (const float*)d_in[2];
    const float* Wih  = (const float*)d_in[3];
    const float* Whh  = (const float*)d_in[4];
    const float* bih  = (const float*)d_in[5];
    const float* bhh  = (const float*)d_in[6];
    float* out = (float*)d_out;

    lstm_kernel<<<1, 256, 0, stream>>>(x, Wih0, Wih, Whh, bih, bhh, out);
}

// Round 6
// 213.600 us; speedup vs baseline: 1.0838x; 1.0193x over previous
//
#include <hip/hip_runtime.h>
#include <math.h>

// Problem constants (from reference)
#define B_ 4096
#define T_ 1024
#define I_ 6
#define H_ 2
#define L_ 5
#define G_ 8            // 4*H packed gates, PyTorch order: rows 0-1=i, 2-3=f, 4-5=g, 6-7=o

// Only batch element B-1 affects the output (softmax(seq[-1,-1])); LSTM is
// batch-independent -> process exactly one sequence.
//
// Serial phase: lane = 2*l + j (layer l, hidden unit j), 2-STEP-DELAY
// diagonal: at global step s, layer l computes timestep t = s - 2l (1032
// steps total). Layer l's cross-layer input h_{l-1}(t) is produced at step
// s-2, so the cross-layer gate contribution pin = pre/bias + wi*hin is
// computed at the TAIL of step s-2 (via dpp + 2 pk_fma) with a full step of
// slack -- off the critical path. The in-step h->h' cycle is:
//   fma(wOwn*h) -> fma(wOth*hoth) -> exp2 -> 1+e -> rcp
//   -> {gvm = fma(-2K2, r2, K2); fvcs = fv*cs} -> csn = fma(iv, gvm, fvcs)
//   -> exp2 -> 1+e -> rcp -> hn = fma(2ov, rh, -ov)      = 11 levels.
// All weights/biases/pre0 pre-scaled by -log2e (i,f,o) or -2log2e (g);
// cell kept pre-scaled: cs = -2log2e*c.

typedef float v2f __attribute__((ext_vector_type(2)));

#define K1 1.4426950408889634f   /* log2(e)   */
#define K2 2.8853900817779268f   /* 2*log2(e) */

template <int CTRL>
__device__ __forceinline__ float dppf(float v) {
    int i = __float_as_int(v);
    int r = __builtin_amdgcn_update_dpp(i, i, CTRL, 0xF, 0xF, false);
    return __int_as_float(r);
}
#define DPP_SHR2 0x112   /* row_shr:2            */
#define DPP_SWAP 0xB1    /* quad_perm [1,0,3,2]  */

__global__ __launch_bounds__(256) void lstm_kernel(
    const float* __restrict__ x,
    const float* __restrict__ Wih0,
    const float* __restrict__ Wih,
    const float* __restrict__ Whh,
    const float* __restrict__ bih,
    const float* __restrict__ bhh,
    float* __restrict__ out)
{
    // pre0[t*8 + j*4 + q]: pre-scaled layer-0 preactivations. 40 pad t-slots
    // of zeros (1032 steps consume Q up to 1033; prefetch reaches 1039).
    __shared__ float pre0[(T_ + 40) * G_];
    // Per-serial-lane (2..9) bias block: 4 identical float4 copies at 32B
    // spacing (ds offsets 0/32/64/96), block stride 36 floats to spread banks.
    __shared__ float zrep[8 * 36 + 12];

    const int tid = threadIdx.x;
    const float* xrow = x + (size_t)(B_ - 1) * T_ * I_;   // x[B-1, :, :]
    const float sc[4] = { -K1, -K1, -K2, -K1 };           // i, f, g, o row scales

    // ---- parallel phase: pre-scaled layer-0 input projections for all t
    float w0s[G_][I_];
    float b0s[G_];
    #pragma unroll
    for (int j = 0; j < 2; ++j)
        #pragma unroll
        for (int q = 0; q < 4; ++q) {
            const int m = j * 4 + q, row = 2 * q + j;
            const float s = sc[q];
            b0s[m] = s * (bih[row] + bhh[row]);
            #pragma unroll
            for (int k = 0; k < I_; ++k) w0s[m][k] = s * Wih0[row * I_ + k];
        }
    for (int t = tid; t < T_; t += 256) {
        float xv[I_];
        #pragma unroll
        for (int k = 0; k < I_; ++k) xv[k] = xrow[t * I_ + k];
        #pragma unroll
        for (int m = 0; m < G_; ++m) {
            float acc = b0s[m];
            #pragma unroll
            for (int k = 0; k < I_; ++k) acc = fmaf(xv[k], w0s[m][k], acc);
            pre0[t * G_ + m] = acc;
        }
    }
    for (int z = tid; z < 40 * G_; z += 256) pre0[T_ * G_ + z] = 0.f;  // pads
    if (tid < 128) {
        // zrep for serial lane zl+2: layer l=(zl+2)>>1, unit j=(zl+2)&1
        const int zl = tid >> 4, k = (tid >> 2) & 3, q = tid & 3;
        const int l = (zl + 2) >> 1, j = (zl + 2) & 1, row = 2 * q + j;
        zrep[zl * 36 + k * 8 + q] = sc[q] * (bih[l * G_ + row] + bhh[l * G_ + row]);
    }
    __syncthreads();
    if (tid >= 64) return;   // serial phase: one wave

    // ---- per-lane constants (pre-scaled weights)
    const int lane = tid;
    const int lraw = lane >> 1;
    const int l = (lraw < L_) ? lraw : (L_ - 1);   // clamp for lanes >= 10
    const int j = lane & 1;

    float wOwn[4], wOth[4], wiOwn[4], wiOth[4];
    #pragma unroll
    for (int q = 0; q < 4; ++q) {
        const int row = 2 * q + j;
        const float s = sc[q];
        wOwn[q] = s * Whh[l * (G_ * H_) + row * H_ + j];
        wOth[q] = s * Whh[l * (G_ * H_) + row * H_ + (1 - j)];
        if (l > 0) {
            wiOwn[q] = s * Wih[(l - 1) * (G_ * H_) + row * H_ + j];
            wiOth[q] = s * Wih[(l - 1) * (G_ * H_) + row * H_ + (1 - j)];
        } else {
            wiOwn[q] = 0.f; wiOth[q] = 0.f;   // layer 0: input term is in pre0
        }
    }
    const v2f wOwn01  = { wOwn[0],  wOwn[1]  }, wOwn23  = { wOwn[2],  wOwn[3]  };
    const v2f wOth01  = { wOth[0],  wOth[1]  }, wOth23  = { wOth[2],  wOth[3]  };
    const v2f wiOwn01 = { wiOwn[0], wiOwn[1] }, wiOwn23 = { wiOwn[2], wiOwn[3] };
    const v2f wiOth01 = { wiOth[0], wiOth[1] }, wiOth23 = { wiOth[2], wiOth[3] };

    // Per-lane LDS stream: lanes 0,1 walk pre0 (128B per 4-quad block);
    // lanes 2-9 sit on their replicated bias block (stride 0 -> every
    // buffered quad holds the bias, so pin tails read the right base).
    const char* pb;
    int stB;
    if (lane < 2) { pb = (const char*)&pre0[lane * 4]; stB = 128; }
    else {
        const int zl = (lane < 10 ? lane : 9) - 2;
        pb = (const char*)&zrep[zl * 36]; stB = 0;
    }

#define LOADBLK(A,B,C,D)                                                    \
    { A = *(const float4*)(pb);      B = *(const float4*)(pb + 32);         \
      C = *(const float4*)(pb + 64); D = *(const float4*)(pb + 96);         \
      pb += stB; }

    float h = 0.f, cs = 0.f;          // cs = -2log2e * c  (pre-scaled cell)
    float hoth = 0.f, hin0 = 0.f, hin1 = 0.f;

    // STEP consumes pin (P01,P23), then at its tail rebuilds the SAME pin
    // registers from quad QN (the layer-0 stream quad for step s+2, or the
    // bias quad) + fresh hin dpps -- consumed two steps later (same parity).
#define STEP_CORE(P01, P23)                                                 \
        const v2f hv = { h, h };                                            \
        v2f a01 = __builtin_elementwise_fma(wOwn01, hv, P01);               \
        v2f a23 = __builtin_elementwise_fma(wOwn23, hv, P23);               \
        const v2f hothv = { hoth, hoth };                                   \
        a01 = __builtin_elementwise_fma(wOth01, hothv, a01);                \
        a23 = __builtin_elementwise_fma(wOth23, hothv, a23);                \
        const float ei = __builtin_amdgcn_exp2f(a01.x);                     \
        const float ef = __builtin_amdgcn_exp2f(a01.y);                     \
        const float eg = __builtin_amdgcn_exp2f(a23.x);                     \
        const float eo = __builtin_amdgcn_exp2f(a23.y);                     \
        const float iv = __builtin_amdgcn_rcpf(1.0f + ei);                  \
        const float fv = __builtin_amdgcn_rcpf(1.0f + ef);                  \
        const float r2 = __builtin_amdgcn_rcpf(1.0f + eg);                  \
        const float ov = __builtin_amdgcn_rcpf(1.0f + eo);                  \
        const float gvm  = fmaf(-2.0f * K2, r2, K2);  /* -K2*tanh(g) */     \
        const float fvcs = fv * cs;                                         \
        const float ovx2 = ov + ov;                                         \
        const float csn  = fmaf(iv, gvm, fvcs);                             \
        const float eh = __builtin_amdgcn_exp2f(csn);                       \
        const float rh = __builtin_amdgcn_rcpf(1.0f + eh);                  \
        const float hn = fmaf(ovx2, rh, -ov);         /* ov*tanh(c) */

#define STEP_TAIL(P01, P23, QN)                                             \
        hoth = dppf<DPP_SWAP>(h);                                           \
        hin0 = dppf<DPP_SHR2>(h);                                           \
        hin1 = dppf<DPP_SHR2>(hoth);                                        \
        {                                                                   \
            const v2f hin0v = { hin0, hin0 };                               \
            const v2f hin1v = { hin1, hin1 };                               \
            v2f q01 = { (QN).x, (QN).y };                                   \
            v2f q23 = { (QN).z, (QN).w };                                   \
            q01 = __builtin_elementwise_fma(wiOwn01, hin0v, q01);           \
            q23 = __builtin_elementwise_fma(wiOwn23, hin0v, q23);           \
            P01 = __builtin_elementwise_fma(wiOth01, hin1v, q01);           \
            P23 = __builtin_elementwise_fma(wiOth23, hin1v, q23);           \
        }

#define STEP(P01, P23, QN)                                                  \
    {                                                                       \
        STEP_CORE(P01, P23)                                                 \
        cs = csn;                                                           \
        h  = hn;                                                            \
        STEP_TAIL(P01, P23, QN)                                             \
    }

#define STEP_M(P01, P23, QN, S)                                             \
    {                                                                       \
        STEP_CORE(P01, P23)                                                 \
        const bool valid = ((S) >= 2 * lraw);                               \
        cs = valid ? csn : 0.0f;                                            \
        h  = valid ? hn  : 0.0f;                                            \
        STEP_TAIL(P01, P23, QN)                                             \
    }

    // 4 register buffers x 4 quads; quad s+2 is consumed by step s's tail.
    float4 A0,A1,A2,A3, B0,B1,B2,B3, C0,C1,C2,C3, D0,D1,D2,D3;
    LOADBLK(A0,A1,A2,A3)   // quads 0-3
    LOADBLK(B0,B1,B2,B3)   // quads 4-7
    LOADBLK(C0,C1,C2,C3)   // quads 8-11
    LOADBLK(D0,D1,D2,D3)   // quads 12-15

    // pin double-buffer (even/odd step parity), init for steps 0 and 1:
    // all hin are zero at warmup start, so pin = quad directly.
    v2f pinE01 = { A0.x, A0.y }, pinE23 = { A0.z, A0.w };
    v2f pinO01 = { A1.x, A1.y }, pinO23 = { A1.z, A1.w };

    // peeled masked warmup: steps 0..7 (t<0 possible while s < 2l <= 8)
    STEP_M(pinE01, pinE23, A2, 0)
    STEP_M(pinO01, pinO23, A3, 1)
    STEP_M(pinE01, pinE23, B0, 2)
    STEP_M(pinO01, pinO23, B1, 3)
    STEP_M(pinE01, pinE23, B2, 4)
    STEP_M(pinO01, pinO23, B3, 5)
    STEP_M(pinE01, pinE23, C0, 6)
    STEP_M(pinO01, pinO23, C1, 7)

    // steady: steps 8..1031 = 64 iterations x 16 steps. Drain (t>=T) needs
    // no mask: stale h only flows toward higher layers at t>=T and never
    // reaches the (layer 4, t=1023) output; pre0 pads are zero.
    for (int it = 0; it < 64; ++it) {
        LOADBLK(A0,A1,A2,A3)
        STEP(pinE01, pinE23, C2) STEP(pinO01, pinO23, C3)
        STEP(pinE01, pinE23, D0) STEP(pinO01, pinO23, D1)
        LOADBLK(B0,B1,B2,B3)
        STEP(pinE01, pinE23, D2) STEP(pinO01, pinO23, D3)
        STEP(pinE01, pinE23, A0) STEP(pinO01, pinO23, A1)
        LOADBLK(C0,C1,C2,C3)
        STEP(pinE01, pinE23, A2) STEP(pinO01, pinO23, A3)
        STEP(pinE01, pinE23, B0) STEP(pinO01, pinO23, B1)
        LOADBLK(D0,D1,D2,D3)
        STEP(pinE01, pinE23, B2) STEP(pinO01, pinO23, B3)
        STEP(pinE01, pinE23, C0) STEP(pinO01, pinO23, C1)
    }
#undef STEP
#undef STEP_M
#undef STEP_CORE
#undef STEP_TAIL
#undef LOADBLK

    // layer 4 = lanes 8 (unit 0) and 9 (unit 1); final state = t = 1023
    const float hf0 = __shfl(h, 8, 64);
    const float hf1 = __shfl(h, 9, 64);
    if (lane == 0) {
        const float mx = fmaxf(hf0, hf1);
        const float e0 = __builtin_amdgcn_exp2f(K1 * (hf0 - mx));
        const float e1 = __builtin_amdgcn_exp2f(K1 * (hf1 - mx));
        const float inv = 1.f / (e0 + e1);
        out[0] = e0 * inv;
        out[1] = e1 * inv;
    }
}

extern "C" void kernel_launch(void* const* d_in, const int* in_sizes, int n_in,
                              void* d_out, int out_size, void* d_ws, size_t ws_size,
                              hipStream_t stream) {
    const float* x    = (const float*)d_in[0];
    // d_in[1] = hidden (unused by the reference forward)
    const float* Wih0 = (const float*)d_in[2];
    const float* Wih  = (const float*)d_in[3];
    const float* Whh  = (const float*)d_in[4];
    const float* bih  = (const float*)d_in[5];
    const float* bhh  = (const float*)d_in[6];
    float* out = (float*)d_out;

    lstm_kernel<<<1, 256, 0, stream>>>(x, Wih0, Wih, Whh, bih, bhh, out);
}

// Round 7
// 207.256 us; speedup vs baseline: 1.1170x; 1.0306x over previous
//
#include <hip/hip_runtime.h>
#include <math.h>

// Problem constants (from reference)
#define B_ 4096
#define T_ 1024
#define I_ 6
#define H_ 2
#define L_ 5
#define G_ 8              // 4*H packed gates, PyTorch rows: 0-1=i, 2-3=f, 4-5=g, 6-7=o
#define PT 1088           // pre0T row pitch (T + 64 zero pad)

// Only batch element B-1 affects the output (softmax(seq[-1,-1])); LSTM is
// batch-independent -> process exactly one sequence.
//
// QUAD-PER-UNIT layout: lane = 8*l + 4*j + q, q in {0:i,1:f,2:g,3:o}.
// Each lane computes ONE gate -> one exp2 + one rcp activates ALL gates of
// ALL layers (trans ops are quarter-rate per-wave; this is the round-7 win:
// 10 trans/step -> 4). Gate results are gathered within each quad by 4
// quad_perm broadcasts; the cell update is computed redundantly in all 4
// lanes of the quad. h is therefore replicated per quad.
//   hoth (other unit, same layer) = row_half_mirror dpp (swaps quads in an
//     8-lane block).
//   cross-layer h (2-step-delay schedule, t = s - 2l): layers 1,3 via
//     row_shr:8 (same 16-row); layer 2 via row_bcast15; layer 4 via
//     row_bcast31. bcast delivers (unit1, unit0) = (from h, from hoth) of
//     the source layer regardless of consumer j; the j-dependent role swap
//     is folded into precomputed per-lane weights wiA/wiB.
// All weights/biases/pre0 pre-scaled by -log2e (i,f,o) or -2log2e (g);
// cell kept pre-scaled cs = -2log2e*c, so both activations are
// rcp(1+exp2(.)) with no multiply. Identical arithmetic to round 6,
// redistributed across lanes.

#define K1 1.4426950408889634f   /* log2(e)   */
#define K2 2.8853900817779268f   /* 2*log2(e) */

template <int CTRL>
__device__ __forceinline__ float dppf(float v) {
    int i = __float_as_int(v);
    int r = __builtin_amdgcn_update_dpp(i, i, CTRL, 0xF, 0xF, false);
    return __int_as_float(r);
}
#define QP_B0   0x00    /* quad_perm [0,0,0,0] */
#define QP_B1   0x55    /* quad_perm [1,1,1,1] */
#define QP_B2   0xAA    /* quad_perm [2,2,2,2] */
#define QP_B3   0xFF    /* quad_perm [3,3,3,3] */
#define ROW_SHR8  0x118
#define HALF_MIRR 0x141
#define BCAST15   0x142
#define BCAST31   0x143

__global__ __launch_bounds__(256) void lstm_kernel(
    const float* __restrict__ x,
    const float* __restrict__ Wih0,
    const float* __restrict__ Wih,
    const float* __restrict__ Whh,
    const float* __restrict__ bih,
    const float* __restrict__ bhh,
    float* __restrict__ out)
{
    // pre0T[r][t], r = 4j+q (lane id of layer 0): pre-scaled layer-0
    // preactivations, transposed so each lane streams its own gate row as
    // float4 (4 steps per load). Cols 1024..1087 zeroed (drain + prefetch).
    __shared__ float pre0T[8 * PT];
    // Per-lane bias quads for lanes 8..63 (layers>=1 + dead lanes): all 4
    // components equal the lane's pre-scaled bias -> stride-0 stream.
    __shared__ float4 biasq[56];

    const int tid = threadIdx.x;
    const float* xrow = x + (size_t)(B_ - 1) * T_ * I_;   // x[B-1, :, :]
    const float sc[4] = { -K1, -K1, -K2, -K1 };           // i, f, g, o scales

    // ---- parallel phase: layer-0 projections for all t (transposed store)
    for (int t = tid; t < T_; t += 256) {
        float xv[I_];
        #pragma unroll
        for (int k = 0; k < I_; ++k) xv[k] = xrow[t * I_ + k];
        #pragma unroll
        for (int r = 0; r < 8; ++r) {
            const int j = r >> 2, q = r & 3, row = 2 * q + j;
            float acc = bih[row] + bhh[row];
            #pragma unroll
            for (int k = 0; k < I_; ++k) acc = fmaf(Wih0[row * I_ + k], xv[k], acc);
            pre0T[r * PT + t] = sc[q] * acc;
        }
    }
    for (int z = tid; z < 8 * 64; z += 256) {             // zero pads
        const int r = z >> 6, col = T_ + (z & 63);
        pre0T[r * PT + col] = 0.f;
    }
    if (tid < 56) {
        float v = 0.f;
        if (tid < 32) {
            const int lane = tid + 8;
            const int l = lane >> 3, j = (lane >> 2) & 1, q = lane & 3;
            const int row = 2 * q + j;
            v = sc[q] * (bih[l * G_ + row] + bhh[l * G_ + row]);
        }
        biasq[tid] = (float4){ v, v, v, v };
    }
    __syncthreads();
    if (tid >= 64) return;   // serial phase: one wave

    // ---- per-lane constants
    const int lane = tid;
    const int lraw = lane >> 3;
    const int l = (lraw < L_) ? lraw : (L_ - 1);
    const int j = (lane >> 2) & 1;
    const int q = lane & 3;
    const int row = 2 * q + j;
    const int twol = 2 * lraw;                 // warmup mask bound
    const bool isl2 = (lane >= 16 && lane < 24);
    const bool isl4 = (lane >= 32);
    const bool isBcast = isl2 || isl4;         // layers fed via row_bcast

    const float s = sc[q];
    const float wOwn = s * Whh[l * (G_ * H_) + row * H_ + j];
    const float wOth = s * Whh[l * (G_ * H_) + row * H_ + (1 - j)];
    float wiOwn = 0.f, wiOth = 0.f;
    if (l > 0) {
        wiOwn = s * Wih[(l - 1) * (G_ * H_) + row * H_ + j];
        wiOth = s * Wih[(l - 1) * (G_ * H_) + row * H_ + (1 - j)];
    }
    // bcast layers receive (v = source unit1 h, w = source unit0 h); shr8
    // layers receive (v = own-j h, w = other-j h). Fold the role swap into
    // the weights: pin = wiA*v + wiB*w.
    const float wiA = isBcast ? (j ? wiOwn : wiOth) : wiOwn;
    const float wiB = isBcast ? (j ? wiOth : wiOwn) : wiOth;

    // Per-lane LDS stream: layer-0 lanes walk their pre0T row (16 B per 4
    // steps); all other lanes sit on their replicated bias quad (stride 0).
    const char* pb;
    int stB;
    if (lane < 8) { pb = (const char*)&pre0T[lane * PT]; stB = 16; }
    else          { pb = (const char*)&biasq[lane - 8];  stB = 0;  }

    float h = 0.f, cs = 0.f, hoth = 0.f;

#define STEP_CORE(PIN)                                                      \
        float aa = fmaf(wOwn, h, PIN);                                      \
        aa = fmaf(wOth, hoth, aa);                                          \
        const float ex = __builtin_amdgcn_exp2f(aa);                        \
        const float rr = __builtin_amdgcn_rcpf(1.0f + ex);                  \
        const float bi = dppf<QP_B0>(rr);   /* iv */                        \
        const float bf = dppf<QP_B1>(rr);   /* fv */                        \
        const float bg = dppf<QP_B2>(rr);   /* r2 of g */                   \
        const float bo = dppf<QP_B3>(rr);   /* ov */                        \
        const float tg = fmaf(-2.0f * K2, bg, K2);  /* -K2*tanh(g) */       \
        const float mm = bi * tg;                                           \
        const float csn = fmaf(bf, cs, mm);                                 \
        const float eh = __builtin_amdgcn_exp2f(csn);                       \
        const float rh = __builtin_amdgcn_rcpf(1.0f + eh);                  \
        const float ov2 = bo + bo;                                          \
        const float hn = fmaf(ov2, rh, -bo);        /* ov*tanh(c) */

#define STEP_TAIL(PIN, QREG)                                                \
        hoth = dppf<HALF_MIRR>(h);                                          \
        {                                                                   \
            const float v1 = dppf<ROW_SHR8>(h);                             \
            const float v2 = dppf<BCAST15>(h);                              \
            const float v3 = dppf<BCAST31>(h);                              \
            const float w1 = dppf<ROW_SHR8>(hoth);                          \
            const float w2 = dppf<BCAST15>(hoth);                           \
            const float w3 = dppf<BCAST31>(hoth);                           \
            float hv = isl2 ? v2 : v1;  hv = isl4 ? v3 : hv;                \
            float hw = isl2 ? w2 : w1;  hw = isl4 ? w3 : hw;                \
            PIN = fmaf(wiA, hv, QREG);                                      \
            PIN = fmaf(wiB, hw, PIN);                                       \
        }

#define STEP(PIN, QREG)                                                     \
    {                                                                       \
        STEP_CORE(PIN)                                                      \
        cs = csn;                                                           \
        h  = hn;                                                            \
        STEP_TAIL(PIN, QREG)                                                \
    }

#define STEP_M(PIN, QREG, S)                                                \
    {                                                                       \
        STEP_CORE(PIN)                                                      \
        const bool valid = ((S) >= twol);                                   \
        cs = valid ? csn : 0.0f;                                            \
        h  = valid ? hn  : 0.0f;                                            \
        STEP_TAIL(PIN, QREG)                                                \
    }

    // Preload: W0,W1 = steps 0-7; ring q0..q7 = steps 8-39.
    float4 W0, W1, q0, q1, q2, q3, q4, q5, q6, q7;
    W0 = *(const float4*)pb; pb += stB;
    W1 = *(const float4*)pb; pb += stB;
    q0 = *(const float4*)pb; pb += stB;
    q1 = *(const float4*)pb; pb += stB;
    q2 = *(const float4*)pb; pb += stB;
    q3 = *(const float4*)pb; pb += stB;
    q4 = *(const float4*)pb; pb += stB;
    q5 = *(const float4*)pb; pb += stB;
    q6 = *(const float4*)pb; pb += stB;
    q7 = *(const float4*)pb; pb += stB;

    // pin double-buffer by step parity; init for steps 0,1 (hin all zero).
    float pinE = W0.x, pinO = W0.y;

    // peeled masked warmup: steps 0..7 (t<0 possible while s < 2l <= 8)
    STEP_M(pinE, W0.z, 0)
    STEP_M(pinO, W0.w, 1)
    STEP_M(pinE, W1.x, 2)
    STEP_M(pinO, W1.y, 3)
    STEP_M(pinE, W1.z, 4)
    STEP_M(pinO, W1.w, 5)
    STEP_M(pinE, q0.x, 6)
    STEP_M(pinO, q0.y, 7)

    // steady: steps 8..1031 = 32 iterations x 32 steps (8 groups of 4).
    // Group m consumes q[m] (steps +4m..+4m+3); its tails read q[m].z/.w and
    // q[m+1].x/.y (step s+2); q[m] is reloaded AFTER use, 28 steps ahead.
    // Drain needs no mask: with the 2-step delay, stale h reaches layer 4
    // only at steps > 1031; pre0T pads are zero.
#define GROUP(QM, QN)                                                       \
        STEP(pinE, (QM).z)                                                  \
        STEP(pinO, (QM).w)                                                  \
        STEP(pinE, (QN).x)                                                  \
        STEP(pinO, (QN).y)                                                  \
        QM = *(const float4*)pb; pb += stB;

    #pragma unroll 1
    for (int it = 0; it < 32; ++it) {
        GROUP(q0, q1) GROUP(q1, q2) GROUP(q2, q3) GROUP(q3, q4)
        GROUP(q4, q5) GROUP(q5, q6) GROUP(q6, q7) GROUP(q7, q0)
    }
#undef GROUP
#undef STEP
#undef STEP_M
#undef STEP_CORE
#undef STEP_TAIL

    // layer 4: unit 0 replicated in lanes 32-35, unit 1 in lanes 36-39.
    const float hf0 = __shfl(h, 32, 64);
    const float hf1 = __shfl(h, 36, 64);
    if (lane == 0) {
        const float mx = fmaxf(hf0, hf1);
        const float e0 = __builtin_amdgcn_exp2f(K1 * (hf0 - mx));
        const float e1 = __builtin_amdgcn_exp2f(K1 * (hf1 - mx));
        const float inv = 1.f / (e0 + e1);
        out[0] = e0 * inv;
        out[1] = e1 * inv;
    }
}

extern "C" void kernel_launch(void* const* d_in, const int* in_sizes, int n_in,
                              void* d_out, int out_size, void* d_ws, size_t ws_size,
                              hipStream_t stream) {
    const float* x    = (const float*)d_in[0];
    // d_in[1] = hidden (unused by the reference forward)
    const float* Wih0 = (const float*)d_in[2];
    const float* Wih  = (const float*)d_in[3];
    const float* Whh  = (const float*)d_in[4];
    const float* bih  = (const float*)d_in[5];
    const float* bhh  = (const float*)d_in[6];
    float* out = (float*)d_out;

    lstm_kernel<<<1, 256, 0, stream>>>(x, Wih0, Wih, Whh, bih, bhh, out);
}